// Round 1
// baseline (2469.909 us; speedup 1.0000x reference)
//
#include <hip/hip_runtime.h>
#include <stdint.h>

#define B_ 128
#define T_ 256
#define F_ 128
#define NCAT_ 32
#define CARD_ 16
#define E_ 8
#define H_ 512
#define INLEN_ 352
#define NCONT_ 96

typedef __bf16 bf16x8 __attribute__((ext_vector_type(8)));
typedef float f32x4 __attribute__((ext_vector_type(4)));
typedef unsigned short ushortx8 __attribute__((ext_vector_type(8)));

__device__ __forceinline__ unsigned short f2bf(float f) {
  unsigned int u = __float_as_uint(f);
  u += 0x7fffu + ((u >> 16) & 1u);   // RNE
  return (unsigned short)(u >> 16);
}
__device__ __forceinline__ float sigm(float x) { return 1.0f / (1.0f + __expf(-x)); }
__device__ __forceinline__ float tanhf_(float x) {
  float a = fabsf(x);
  float e = __expf(-2.0f * a);
  float t = (1.0f - e) / (1.0f + e);
  return x < 0.0f ? -t : t;
}

// ---------------- init: zero the 4 tagged h ping-pong slots (tag 0 == h_{-1}=0) ----------------
__global__ void k_initH(unsigned int* Hbuf) {
  __hip_atomic_store(&Hbuf[blockIdx.x * 256 + threadIdx.x], 0u, __ATOMIC_RELAXED,
                     __HIP_MEMORY_SCOPE_AGENT);
}

// ---------------- prep: W_in transposed -> bf16 (512 x 352) ----------------
__global__ void k_prep(const float* __restrict__ W_in, unsigned short* __restrict__ W_inT) {
  int id = blockIdx.x * 256 + threadIdx.x;
  if (id < 512 * INLEN_) {
    int n = id / INLEN_;
    int k = id - n * INLEN_;
    W_inT[id] = f2bf(W_in[k * 512 + n]);
  }
}

// ---------------- features: FEAT[t*128+b][352] bf16 ----------------
__global__ void k_feat(const int* __restrict__ unscaled, const float* __restrict__ scaled,
                       const float* __restrict__ emb, unsigned short* __restrict__ FEAT) {
  int row = blockIdx.x * 4 + (threadIdx.x >> 6);
  int t = row >> 7, b = row & 127;
  const int base = (b * T_ + t) * F_;
  for (int jj = (threadIdx.x & 63); jj < INLEN_; jj += 64) {
    int ci = jj / 11;
    int pos = jj - ci * 11;
    float v;
    if (pos < 8) {
      int cid = unscaled[base + 4 * ci];
      v = emb[(ci * CARD_ + cid) * E_ + pos];
    } else {
      v = scaled[base + 4 * ci + 1 + (pos - 8)];
    }
    FEAT[row * INLEN_ + jj] = f2bf(v);
  }
}

// ---------------- GEMM1: X = relu(FEAT @ W_in + b_in), bf16 out ----------------
__global__ __launch_bounds__(256) void k_gemm1(const unsigned short* __restrict__ FEAT,
                                               const unsigned short* __restrict__ W_inT,
                                               const float* __restrict__ b_in,
                                               unsigned short* __restrict__ X) {
  __shared__ __align__(16) unsigned short As[128 * 40];
  __shared__ __align__(16) unsigned short Bs[128 * 40];
  const int tid = threadIdx.x;
  const int Mtile = blockIdx.x >> 2;
  const int N0 = (blockIdx.x & 3) * 128;
  const int wv = tid >> 6, ln = tid & 63;
  const int lrow = ln & 15, lq = ln >> 4;
  f32x4 acc[2][8];
#pragma unroll
  for (int i = 0; i < 2; ++i)
#pragma unroll
    for (int j = 0; j < 8; ++j) acc[i][j] = (f32x4){0.f, 0.f, 0.f, 0.f};

  for (int kc = 0; kc < 11; ++kc) {
    int k0 = kc * 32;
#pragma unroll
    for (int i = 0; i < 2; ++i) {
      int c = i * 256 + tid;
      int row = c >> 2;
      int col = (c & 3) * 8;
      uint4 va = *(const uint4*)&FEAT[(Mtile * 128 + row) * INLEN_ + k0 + col];
      *(uint4*)&As[row * 40 + col] = va;
      uint4 vb = *(const uint4*)&W_inT[(N0 + row) * INLEN_ + k0 + col];
      *(uint4*)&Bs[row * 40 + col] = vb;
    }
    __syncthreads();
    bf16x8 af[2];
#pragma unroll
    for (int mt = 0; mt < 2; ++mt) {
      int r = wv * 32 + mt * 16 + lrow;
      af[mt] = __builtin_bit_cast(bf16x8, *(const ushortx8*)&As[r * 40 + lq * 8]);
    }
#pragma unroll
    for (int ntl = 0; ntl < 8; ++ntl) {
      bf16x8 bf = __builtin_bit_cast(bf16x8, *(const ushortx8*)&Bs[(ntl * 16 + lrow) * 40 + lq * 8]);
      acc[0][ntl] = __builtin_amdgcn_mfma_f32_16x16x32_bf16(af[0], bf, acc[0][ntl], 0, 0, 0);
      acc[1][ntl] = __builtin_amdgcn_mfma_f32_16x16x32_bf16(af[1], bf, acc[1][ntl], 0, 0, 0);
    }
    __syncthreads();
  }
#pragma unroll
  for (int mt = 0; mt < 2; ++mt)
#pragma unroll
    for (int ntl = 0; ntl < 8; ++ntl) {
      int n = N0 + ntl * 16 + lrow;
      float bias = b_in[n];
#pragma unroll
      for (int r = 0; r < 4; ++r) {
        int row = Mtile * 128 + wv * 32 + mt * 16 + lq * 4 + r;
        float v = acc[mt][ntl][r] + bias;
        v = v > 0.0f ? v : 0.0f;
        X[row * H_ + n] = f2bf(v);
      }
    }
}

// ---------------- persistent LSTM: 8 groups x 16 blocks, 512 thr ----------------
// Sync model: tagged data words. Hbuf word = (tag16<<16)|bf16, tag = t+1.
// Depth-2 ping-pong per cell; WAR-safe because overwrite at t+2 is >=2 group
// dependency hops after every peer's read at t. Zero-init == tag0 == h_{-1}=0.
__device__ __forceinline__ void stageX(unsigned short* dst, const unsigned short* src, int tid) {
#pragma unroll
  for (int i = 0; i < 2; ++i) {
    int c = i * 512 + tid;
    int row = c >> 6;
    int col = (c & 63) * 8;
    uint4 v = *(const uint4*)&src[row * H_ + col];
    *(uint4*)&dst[row * 520 + col] = v;
  }
}

__global__ __launch_bounds__(512, 2) void k_lstm(
    const float* __restrict__ Wih0, const float* __restrict__ Whh0,
    const float* __restrict__ bih0, const float* __restrict__ bhh0,
    const float* __restrict__ Wih1, const float* __restrict__ Whh1,
    const float* __restrict__ bih1, const float* __restrict__ bhh1,
    const unsigned short* __restrict__ X, unsigned int* __restrict__ Hbuf,
    float* __restrict__ out_h, float* __restrict__ out_c) {
  __shared__ __align__(16) unsigned short hS[16 * 520];
  __shared__ __align__(16) unsigned short xS[16 * 520];
  __shared__ __align__(16) float gS[128 * 20];
  __shared__ float b0cS[128], b1cS[128];

  const int tid = threadIdx.x;
  const int group = blockIdx.x >> 4;   // 0..7 : batch rows r0..r0+15
  const int bc = blockIdx.x & 15;      // 0..15 : h-cols j0..j0+31
  const int j0 = bc * 32;
  const int r0 = group * 16;
  const int wv = tid >> 6, ln = tid & 63;
  const int lrow = ln & 15, lq = ln >> 4;
  const int n_local = wv * 16 + lrow;                              // 0..127 gate-col in block
  const int gcol = ((n_local >> 5) << 9) + j0 + (n_local & 31);    // gate*512 + hcol

  // one-time: weight B-fragments in registers (bf16), combined biases in LDS
  bf16x8 Bf0[32], Bf1[16];
  {
    const float* s0 = Wih0 + gcol * H_;
    const float* s1 = Whh0 + gcol * H_;
#pragma unroll
    for (int ks = 0; ks < 32; ++ks) {
      int k = (ks & 15) * 32 + lq * 8;
      const float* s = (ks < 16) ? (s0 + k) : (s1 + k);
      ushortx8 u;
#pragma unroll
      for (int j = 0; j < 8; ++j) u[j] = f2bf(s[j]);
      Bf0[ks] = __builtin_bit_cast(bf16x8, u);
    }
    const float* sa = Wih1 + gcol * H_;
    const float* sb = Whh1 + gcol * H_;
#pragma unroll
    for (int ks = 0; ks < 16; ++ks) {
      int k = ks * 32 + lq * 8;
      ushortx8 u;
#pragma unroll
      for (int j = 0; j < 8; ++j) u[j] = f2bf(sa[k + j] + sb[k + j]);
      Bf1[ks] = __builtin_bit_cast(bf16x8, u);
    }
  }
  if (tid < 128) {
    int g2 = ((tid >> 5) << 9) + j0 + (tid & 31);
    b0cS[tid] = bih0[g2] + bhh0[g2];
    b1cS[tid] = bih1[g2] + bhh1[g2];
  }

  unsigned int* const HA0 = Hbuf;
  unsigned int* const HA1 = Hbuf + 65536;
  unsigned int* const HB0 = Hbuf + 131072;
  unsigned int* const HB1 = Hbuf + 196608;

  const int eb = tid & 15, ej = tid >> 4;   // elementwise ownership: row eb, h-col j0+ej
  const int fragOff = lrow * 520 + lq * 8;
  // poll/stage assignment: 8 u64 (2 tagged cols each) per thread
  const int rb = tid >> 8;        // 0..1 : row block (8 rows)
  const int c2 = tid & 255;       // col pair index
  const int srcOff = (r0 + rb * 8) * 256 + c2;   // in u64 units
  const int ldsBase = (rb * 8) * 520 + c2 * 2;   // in short units
  float c_reg = 0.0f, cp_v = 0.0f;
  int guard = 0;

  stageX(xS, X + r0 * H_, tid);   // preload X_0
  __syncthreads();

#pragma unroll 1
  for (int t = 0; t < T_; ++t) {
    // ======== cell 0 ========
    f32x4 acc0 = (f32x4){0.f, 0.f, 0.f, 0.f};
    f32x4 acc1 = (f32x4){0.f, 0.f, 0.f, 0.f};
#pragma unroll
    for (int ks = 0; ks < 16; ks += 2) {   // x-part: independent of peers -> before poll
      bf16x8 a0 = __builtin_bit_cast(bf16x8, *(const ushortx8*)&xS[fragOff + ks * 32]);
      acc0 = __builtin_amdgcn_mfma_f32_16x16x32_bf16(a0, Bf0[ks], acc0, 0, 0, 0);
      bf16x8 a1 = __builtin_bit_cast(bf16x8, *(const ushortx8*)&xS[fragOff + (ks + 1) * 32]);
      acc1 = __builtin_amdgcn_mfma_f32_16x16x32_bf16(a1, Bf0[ks + 1], acc1, 0, 0, 0);
    }
    {   // poll+stage h1_{t-1}: tag t, slot (t+1)&1
      const unsigned long long* src =
          (const unsigned long long*)(((t + 1) & 1) ? HB1 : HB0) + srcOff;
      const unsigned int expect = (unsigned int)t;
      unsigned long long vv[8];
#pragma unroll
      for (int i = 0; i < 8; ++i)
        vv[i] = __hip_atomic_load(src + i * 256, __ATOMIC_RELAXED, __HIP_MEMORY_SCOPE_AGENT);
      unsigned int need = 0xFFu;
      while (__any((int)(need != 0u))) {
        unsigned int nn = 0u;
#pragma unroll
        for (int i = 0; i < 8; ++i)
          if (need & (1u << i)) {
            unsigned int lo = (unsigned int)vv[i], hi = (unsigned int)(vv[i] >> 32);
            if ((lo >> 16) != expect || (hi >> 16) != expect) {
              nn |= 1u << i;
              vv[i] = __hip_atomic_load(src + i * 256, __ATOMIC_RELAXED, __HIP_MEMORY_SCOPE_AGENT);
            }
          }
        need = nn;
        if (++guard > 4000000) break;   // deadlock bail -> wrong answer instead of hang
      }
#pragma unroll
      for (int i = 0; i < 8; ++i) {
        unsigned int lo = (unsigned int)vv[i], hi = (unsigned int)(vv[i] >> 32);
        *(unsigned int*)&hS[ldsBase + i * 520] = (lo & 0xFFFFu) | (hi << 16);
      }
    }
    __syncthreads();
#pragma unroll
    for (int ks = 0; ks < 16; ks += 2) {
      bf16x8 a0 = __builtin_bit_cast(bf16x8, *(const ushortx8*)&hS[fragOff + ks * 32]);
      acc0 = __builtin_amdgcn_mfma_f32_16x16x32_bf16(a0, Bf0[16 + ks], acc0, 0, 0, 0);
      bf16x8 a1 = __builtin_bit_cast(bf16x8, *(const ushortx8*)&hS[fragOff + (ks + 1) * 32]);
      acc1 = __builtin_amdgcn_mfma_f32_16x16x32_bf16(a1, Bf0[16 + ks + 1], acc1, 0, 0, 0);
    }
    *(f32x4*)&gS[n_local * 20 + lq * 4] = acc0 + acc1;
    __syncthreads();
    {
      float iv = gS[(ej) * 20 + eb] + b0cS[ej];
      float fv = gS[(32 + ej) * 20 + eb] + b0cS[32 + ej];
      float gv = gS[(64 + ej) * 20 + eb] + b0cS[64 + ej];
      float ov = gS[(96 + ej) * 20 + eb] + b0cS[96 + ej];
      cp_v = sigm(fv) * c_reg + sigm(iv) * tanhf_(gv);
      float hv = sigm(ov) * tanhf_(cp_v);
      unsigned int pk = ((unsigned int)(t + 1) << 16) | (unsigned int)f2bf(hv);
      __hip_atomic_store((((t & 1) ? HA1 : HA0) + (r0 + eb) * 512 + j0 + ej), pk,
                         __ATOMIC_RELAXED, __HIP_MEMORY_SCOPE_AGENT);
    }
    asm volatile("" ::: "memory");   // keep publish ordered before the next poll loop

    // ======== cell 1 ========
    if (t + 1 < T_) stageX(xS, X + ((t + 1) * B_ + r0) * H_, tid);   // prefetch next X
    {   // poll+stage h0_t: tag t+1, slot t&1
      const unsigned long long* src = (const unsigned long long*)((t & 1) ? HA1 : HA0) + srcOff;
      const unsigned int expect = (unsigned int)(t + 1);
      unsigned long long vv[8];
#pragma unroll
      for (int i = 0; i < 8; ++i)
        vv[i] = __hip_atomic_load(src + i * 256, __ATOMIC_RELAXED, __HIP_MEMORY_SCOPE_AGENT);
      unsigned int need = 0xFFu;
      while (__any((int)(need != 0u))) {
        unsigned int nn = 0u;
#pragma unroll
        for (int i = 0; i < 8; ++i)
          if (need & (1u << i)) {
            unsigned int lo = (unsigned int)vv[i], hi = (unsigned int)(vv[i] >> 32);
            if ((lo >> 16) != expect || (hi >> 16) != expect) {
              nn |= 1u << i;
              vv[i] = __hip_atomic_load(src + i * 256, __ATOMIC_RELAXED, __HIP_MEMORY_SCOPE_AGENT);
            }
          }
        need = nn;
        if (++guard > 4000000) break;
      }
#pragma unroll
      for (int i = 0; i < 8; ++i) {
        unsigned int lo = (unsigned int)vv[i], hi = (unsigned int)(vv[i] >> 32);
        *(unsigned int*)&hS[ldsBase + i * 520] = (lo & 0xFFFFu) | (hi << 16);
      }
    }
    __syncthreads();
    acc0 = (f32x4){0.f, 0.f, 0.f, 0.f};
    acc1 = (f32x4){0.f, 0.f, 0.f, 0.f};
#pragma unroll
    for (int ks = 0; ks < 16; ks += 2) {
      bf16x8 a0 = __builtin_bit_cast(bf16x8, *(const ushortx8*)&hS[fragOff + ks * 32]);
      acc0 = __builtin_amdgcn_mfma_f32_16x16x32_bf16(a0, Bf1[ks], acc0, 0, 0, 0);
      bf16x8 a1 = __builtin_bit_cast(bf16x8, *(const ushortx8*)&hS[fragOff + (ks + 1) * 32]);
      acc1 = __builtin_amdgcn_mfma_f32_16x16x32_bf16(a1, Bf1[ks + 1], acc1, 0, 0, 0);
    }
    *(f32x4*)&gS[n_local * 20 + lq * 4] = acc0 + acc1;
    __syncthreads();
    {
      float iv = gS[(ej) * 20 + eb] + b1cS[ej];
      float fv = gS[(32 + ej) * 20 + eb] + b1cS[32 + ej];
      float gv = gS[(64 + ej) * 20 + eb] + b1cS[64 + ej];
      float ov = gS[(96 + ej) * 20 + eb] + b1cS[96 + ej];
      float cn = sigm(fv) * cp_v + sigm(iv) * tanhf_(gv);
      float hv = sigm(ov) * tanhf_(cn);
      c_reg = cn;
      unsigned int pk = ((unsigned int)(t + 1) << 16) | (unsigned int)f2bf(hv);
      __hip_atomic_store((((t & 1) ? HB1 : HB0) + (r0 + eb) * 512 + j0 + ej), pk,
                         __ATOMIC_RELAXED, __HIP_MEMORY_SCOPE_AGENT);
      if (t == T_ - 1) {
        out_h[(r0 + eb) * H_ + j0 + ej] = hv;
        out_c[(r0 + eb) * H_ + j0 + ej] = cn;
      }
    }
    asm volatile("" ::: "memory");
  }
}

// ---------------- heads: cont_out + cls_out (f32) ----------------
__global__ __launch_bounds__(256) void k_heads(const float* __restrict__ h,
                                               const float* __restrict__ W_out,
                                               const float* __restrict__ b_out,
                                               const float* __restrict__ W_cls,
                                               const float* __restrict__ b_cls,
                                               float* __restrict__ out) {
  int o = blockIdx.x * 256 + threadIdx.x;
  if (o < B_ * NCONT_) {
    int b = o / NCONT_;
    int n = o - b * NCONT_;
    float acc = b_out[n];
    const float* hb = h + b * H_;
    for (int k = 0; k < H_; k += 4) {
      acc += hb[k] * W_out[k * NCONT_ + n] + hb[k + 1] * W_out[(k + 1) * NCONT_ + n] +
             hb[k + 2] * W_out[(k + 2) * NCONT_ + n] + hb[k + 3] * W_out[(k + 3) * NCONT_ + n];
    }
    out[o] = acc;
  } else {
    int oo = o - B_ * NCONT_;
    int b = oo >> 9;
    int r = oo & 511;
    int ci = r >> 4, cd = r & 15;
    float acc = b_cls[ci * 16 + cd];
    const float* hb = h + b * H_;
    const float* wc = W_cls + ci * 512 * 16 + cd;
    for (int k = 0; k < H_; k += 4) {
      acc += hb[k] * wc[k * 16] + hb[k + 1] * wc[(k + 1) * 16] + hb[k + 2] * wc[(k + 2) * 16] +
             hb[k + 3] * wc[(k + 3) * 16];
    }
    out[B_ * NCONT_ + oo] = acc;
  }
}

extern "C" void kernel_launch(void* const* d_in, const int* in_sizes, int n_in,
                              void* d_out, int out_size, void* d_ws, size_t ws_size,
                              hipStream_t stream) {
  const int* unscaled = (const int*)d_in[0];
  const float* scaled = (const float*)d_in[1];
  const float* emb = (const float*)d_in[2];
  const float* W_in = (const float*)d_in[3];
  const float* b_in = (const float*)d_in[4];
  const float* Wih0 = (const float*)d_in[5];
  const float* Whh0 = (const float*)d_in[6];
  const float* bih0 = (const float*)d_in[7];
  const float* bhh0 = (const float*)d_in[8];
  const float* Wih1 = (const float*)d_in[9];
  const float* Whh1 = (const float*)d_in[10];
  const float* bih1 = (const float*)d_in[11];
  const float* bhh1 = (const float*)d_in[12];
  const float* W_out = (const float*)d_in[13];
  const float* b_out = (const float*)d_in[14];
  const float* W_cls = (const float*)d_in[15];
  const float* b_cls = (const float*)d_in[16];

  // Layout: FEAT [0, 23068672) is dead after k_gemm1 -> Hbuf (1 MB tagged h
  // ping-pong, 4 slots x 128x512 u32) overlays its first 1 MB, init'ed after gemm1.
  const size_t o_feat = 0;                       // 23068672
  const size_t o_X = 23068672;                   // 33554432
  const size_t o_WinT = 56623104;                // 360448
  const size_t WS_NEED = 56983552;
  if (ws_size < WS_NEED) return;

  char* ws = (char*)d_ws;
  unsigned short* FEAT = (unsigned short*)(ws + o_feat);
  unsigned short* X = (unsigned short*)(ws + o_X);
  unsigned short* W_inT = (unsigned short*)(ws + o_WinT);
  unsigned int* Hbuf = (unsigned int*)(ws + o_feat);   // overlays FEAT

  float* out = (float*)d_out;
  float* out_h = out + 77824;
  float* out_c = out + 143360;

  k_prep<<<704, 256, 0, stream>>>(W_in, W_inT);
  k_feat<<<8192, 256, 0, stream>>>(unscaled, scaled, emb, FEAT);
  k_gemm1<<<1024, 256, 0, stream>>>(FEAT, W_inT, b_in, X);
  k_initH<<<1024, 256, 0, stream>>>(Hbuf);
  k_lstm<<<128, 512, 0, stream>>>(Wih0, Whh0, bih0, bhh0, Wih1, Whh1, bih1, bhh1, X, Hbuf,
                                  out_h, out_c);
  k_heads<<<304, 256, 0, stream>>>(out_h, W_out, b_out, W_cls, b_cls, out);
}